// Round 3
// baseline (143.193 us; speedup 1.0000x reference)
//
#include <hip/hip_runtime.h>
#include <math.h>

typedef _Float16 f16;
typedef __attribute__((ext_vector_type(2))) _Float16 f16x2;
typedef __attribute__((ext_vector_type(4))) _Float16 f16x4;
typedef __attribute__((ext_vector_type(8))) _Float16 f16x8;
typedef __attribute__((ext_vector_type(4))) float f32x4;

#define NBATCH 8
#define WSA_ELE 36864      // 32*1152 (w_off padded to 32 rows, k-major, frag-swizzled)
#define WSB_ELE 147456     // 128*1152 (w_def, k-major, frag-swizzled)
// workspace byte offsets
#define OFF_WSB  73728
#define OFF_XT   368640

// ---------------- prep: weights -> fp16, k-major, MFMA-fragment-swizzled ----------------
// swizzled element e = ((ch*NFRAG + mt)*64 + lane)*8 + j holds
// W[row = mt*16 + (lane&15)][kidx = ch*32 + (lane>>4)*8 + j], kidx = k*128 + cc.
__global__ __launch_bounds__(256) void prep_w_kernel(const float* __restrict__ w_off,
                                                     const float* __restrict__ w_def,
                                                     f16* __restrict__ wsA,
                                                     f16* __restrict__ wsB) {
  int i = blockIdx.x * 256 + threadIdx.x;
  if (i < WSA_ELE) {
    int j = i & 7, lane = (i >> 3) & 63, fm = i >> 9;
    int ch = fm >> 1, mt = fm & 1;
    int row = mt * 16 + (lane & 15);
    int kidx = ch * 32 + (lane >> 4) * 8 + j;
    int k = kidx >> 7, cc = kidx & 127;
    float v = (row < 27) ? w_off[row * 1152 + cc * 9 + k] : 0.0f;
    wsA[i] = (f16)v;
  } else {
    int e = i - WSA_ELE;
    int j = e & 7, lane = (e >> 3) & 63, fm = e >> 9;
    int ch = fm >> 3, mt = fm & 7;
    int row = mt * 16 + (lane & 15);
    int kidx = ch * 32 + (lane >> 4) * 8 + j;
    int k = kidx >> 7, cc = kidx & 127;
    wsB[e] = (f16)w_def[row * 1152 + cc * 9 + k];
  }
}

// ---------------- transpose: x NCHW fp32 -> x_t NHWC fp16 (vectorized) ----------------
__global__ __launch_bounds__(256) void transpose_kernel(const float* __restrict__ x,
                                                        f16* __restrict__ xt) {
  __shared__ __align__(16) f16 s_t[128 * 68];   // pitch 68: 8B-aligned rows
  const int t = threadIdx.x;
  const int b = blockIdx.x >> 6;
  const int pos0 = (blockIdx.x & 63) << 6;
  const float* xb = x + ((size_t)b << 19);
  #pragma unroll
  for (int it = 0; it < 8; ++it) {
    int i = it * 256 + t;
    int c = i >> 4, p4 = (i & 15) << 2;
    float4 v = *(const float4*)&xb[c * 4096 + pos0 + p4];
    f16x4 h = {(f16)v.x, (f16)v.y, (f16)v.z, (f16)v.w};
    *(f16x4*)&s_t[c * 68 + p4] = h;
  }
  __syncthreads();
  f16* xtb = xt + ((size_t)b << 19);
  #pragma unroll
  for (int it = 0; it < 8; ++it) {
    int i = it * 256 + t;
    int p = i >> 5, c4 = (i & 31) << 2;
    f16x4 h = {s_t[(c4    ) * 68 + p],
               s_t[(c4 + 1) * 68 + p],
               s_t[(c4 + 2) * 68 + p],
               s_t[(c4 + 3) * 68 + p]};
    *(f16x4*)&xtb[(size_t)(pos0 + p) * 128 + c4] = h;
  }
}

// ---------------- fused: offset conv (-> LDS) + bilinear table + DCN main loop ----------------
// One block per (b, ho). Phase 3 is BARRIER-FREE: A fragments come straight from
// global wsB (identical addresses across waves -> L1 broadcast) and both the A
// stream and the 4 bilinear gathers are register-prefetched ONE CHUNK AHEAD.
// Each wave pipelines independently; the compiler emits counted vmcnt waits.
__global__ __launch_bounds__(256) void fused_dcn_kernel(const f16* __restrict__ xt,
                                                        const f16* __restrict__ wsA,
                                                        const f16* __restrict__ wsB,
                                                        const float* __restrict__ b_off,
                                                        const float* __restrict__ b_def,
                                                        float* __restrict__ out) {
  __shared__ float  s_off[27 * 65];             // offset-conv row, pitch 65 (conflict-free)
  __shared__ uint4  s_ofs[576];                 // per-(k,px) corner byte-offsets
  __shared__ float4 s_wt[576];                  // per-(k,px) modulated weights
  const int t = threadIdx.x;
  const int b = blockIdx.x >> 6, ho = blockIdx.x & 63;
  const int lane = t & 63, wid = t >> 6;
  const int q = lane >> 4, li = lane & 15;
  const int px = (wid << 4) + li;
  const char* xtb = (const char*)xt + ((size_t)b << 20);

  // ---- phase 1: offset conv, M=32 (27 live rows), barrier-free im2col MFMA ----
  {
    f32x4 acc0 = {0.f, 0.f, 0.f, 0.f}, acc1 = {0.f, 0.f, 0.f, 0.f};
    for (int k = 0; k < 9; ++k) {
      const int ky = k / 3, kx = k - ky * 3;
      const int y = ho + ky - 1;
      const int xx = px + kx - 1;
      const bool valid = ((unsigned)y < 64u) && ((unsigned)xx < 64u);
      const int pos = min(max(y, 0), 63) * 64 + min(max(xx, 0), 63);
      const int voff = pos * 256 + q * 16;   // bytes; +c4*64 as imm below
      #pragma unroll
      for (int c4 = 0; c4 < 4; ++c4) {
        union { uint4 u; f16x8 v; } bu;
        bu.u = *(const uint4*)(xtb + voff + c4 * 64);
        if (!valid) { bu.u.x = 0u; bu.u.y = 0u; bu.u.z = 0u; bu.u.w = 0u; }
        const int ch = k * 4 + c4;
        f16x8 a0 = *(const f16x8*)&wsA[(ch * 2    ) * 512 + lane * 8];
        f16x8 a1 = *(const f16x8*)&wsA[(ch * 2 + 1) * 512 + lane * 8];
        acc0 = __builtin_amdgcn_mfma_f32_16x16x32_f16(a0, bu.v, acc0, 0, 0, 0);
        acc1 = __builtin_amdgcn_mfma_f32_16x16x32_f16(a1, bu.v, acc1, 0, 0, 0);
      }
    }
    #pragma unroll
    for (int mt = 0; mt < 2; ++mt) {
      f32x4 a = mt ? acc1 : acc0;
      #pragma unroll
      for (int r = 0; r < 4; ++r) {
        int oc = mt * 16 + q * 4 + r;
        if (oc < 27) {
          float v = a[r] + b_off[oc];
          if (oc >= 18) v = 1.0f / (1.0f + __expf(-v));
          s_off[oc * 65 + px] = v;
        }
      }
    }
  }
  __syncthreads();   // offset row ready in LDS

  // ---- phase 2: bilinear table (ci-invariant corner offsets + premultiplied weights) ----
  for (int f = t; f < 576; f += 256) {
    int k = f >> 6, p = f & 63;
    int ky = k / 3, kx = k - ky * 3;
    float oy = s_off[(2 * k    ) * 65 + p];
    float ox = s_off[(2 * k + 1) * 65 + p];
    float m  = s_off[(18 + k   ) * 65 + p];
    float py  = oy + (float)(ho + ky - 1);
    float pxf = ox + (float)(p + kx - 1);
    float y0f = floorf(py), x0f = floorf(pxf);
    float wy = py - y0f, wx = pxf - x0f;
    int y0 = (int)y0f, x0 = (int)x0f;
    int y1 = y0 + 1, x1 = x0 + 1;
    bool y0v = (unsigned)y0 < 64u, y1v = (unsigned)y1 < 64u;
    bool x0v = (unsigned)x0 < 64u, x1v = (unsigned)x1 < 64u;
    int y0c = min(max(y0, 0), 63), y1c = min(max(y1, 0), 63);
    int x0c = min(max(x0, 0), 63), x1c = min(max(x1, 0), 63);
    uint4 o4;
    o4.x = (unsigned)((y0c * 64 + x0c) * 256);
    o4.y = (unsigned)((y0c * 64 + x1c) * 256);
    o4.z = (unsigned)((y1c * 64 + x0c) * 256);
    o4.w = (unsigned)((y1c * 64 + x1c) * 256);
    float4 w4;
    w4.x = (y0v && x0v) ? (1.f - wy) * (1.f - wx) * m : 0.f;
    w4.y = (y0v && x1v) ? (1.f - wy) * wx         * m : 0.f;
    w4.z = (y1v && x0v) ? wy         * (1.f - wx) * m : 0.f;
    w4.w = (y1v && x1v) ? wy         * wx         * m : 0.f;
    s_ofs[f] = o4;
    s_wt[f]  = w4;
  }
  __syncthreads();   // table ready

  // ---- phase 3: barrier-free, dual register-prefetched (A + gathers) ----
  f32x4 acc[8];
  #pragma unroll
  for (int mt = 0; mt < 8; ++mt) acc[mt] = (f32x4){0.f, 0.f, 0.f, 0.f};

  typedef union { uint4 u; f16x8 v; f16x2 h[4]; } AU;
  AU Ac[8], An[8], Gc[4], Gn[4];

  // prologue: issue chunk 0 (A + gathers)
  {
    #pragma unroll
    for (int mt = 0; mt < 8; ++mt)
      Ac[mt].u = *(const uint4*)&wsB[(mt * 64 + lane) * 8];
    const uint4 o4 = s_ofs[px];
    const unsigned add = q * 16;
    Gc[0].u = *(const uint4*)(xtb + o4.x + add);
    Gc[1].u = *(const uint4*)(xtb + o4.y + add);
    Gc[2].u = *(const uint4*)(xtb + o4.z + add);
    Gc[3].u = *(const uint4*)(xtb + o4.w + add);
  }

  #pragma unroll 2
  for (int ch = 0; ch < 36; ++ch) {
    // issue next chunk's loads first (consumed a full iteration later)
    if (ch < 35) {
      const f16* ab = wsB + (ch + 1) * 4096;
      #pragma unroll
      for (int mt = 0; mt < 8; ++mt)
        An[mt].u = *(const uint4*)&ab[(mt * 64 + lane) * 8];
      const int kn = (ch + 1) >> 2, c4n = (ch + 1) & 3;
      const uint4 o4 = s_ofs[kn * 64 + px];
      const unsigned add = q * 16 + c4n * 64;
      Gn[0].u = *(const uint4*)(xtb + o4.x + add);
      Gn[1].u = *(const uint4*)(xtb + o4.y + add);
      Gn[2].u = *(const uint4*)(xtb + o4.z + add);
      Gn[3].u = *(const uint4*)(xtb + o4.w + add);
    }
    // pack current chunk's B fragment
    const int k = ch >> 2;
    const float4 w4 = s_wt[k * 64 + px];
    const f16 h0 = (f16)w4.x, h1 = (f16)w4.y, h2 = (f16)w4.z, h3 = (f16)w4.w;
    const f16x2 wp0 = {h0, h0}, wp1 = {h1, h1}, wp2 = {h2, h2}, wp3 = {h3, h3};
    union { f16x2 h[4]; f16x8 v; } bf;
    #pragma unroll
    for (int i = 0; i < 4; ++i) {
      f16x2 s = Gc[0].h[i] * wp0;
      s = s + Gc[1].h[i] * wp1;
      s = s + Gc[2].h[i] * wp2;
      s = s + Gc[3].h[i] * wp3;
      bf.h[i] = s;
    }
    #pragma unroll
    for (int mt = 0; mt < 8; ++mt)
      acc[mt] = __builtin_amdgcn_mfma_f32_16x16x32_f16(Ac[mt].v, bf.v, acc[mt], 0, 0, 0);
    // rotate (copy-propagated to renaming under unroll)
    #pragma unroll
    for (int mt = 0; mt < 8; ++mt) Ac[mt] = An[mt];
    #pragma unroll
    for (int i = 0; i < 4; ++i) Gc[i] = Gn[i];
  }

  float* o = out + (size_t)b * 128 * 4096 + ho * 64 + px;
  #pragma unroll
  for (int mt = 0; mt < 8; ++mt) {
    #pragma unroll
    for (int r = 0; r < 4; ++r) {
      int oc = mt * 16 + q * 4 + r;
      o[oc * 4096] = acc[mt][r] + b_def[oc];
    }
  }
}

extern "C" void kernel_launch(void* const* d_in, const int* in_sizes, int n_in,
                              void* d_out, int out_size, void* d_ws, size_t ws_size,
                              hipStream_t stream) {
  const float* x     = (const float*)d_in[0];
  const float* w_off = (const float*)d_in[1];
  const float* b_off = (const float*)d_in[2];
  const float* w_def = (const float*)d_in[3];
  const float* b_def = (const float*)d_in[4];
  float* out = (float*)d_out;

  f16* wsA = (f16*)d_ws;
  f16* wsB = (f16*)((char*)d_ws + OFF_WSB);
  f16* xt  = (f16*)((char*)d_ws + OFF_XT);

  prep_w_kernel<<<dim3((WSA_ELE + WSB_ELE) / 256), dim3(256), 0, stream>>>(w_off, w_def, wsA, wsB);
  transpose_kernel<<<dim3(NBATCH * 64), dim3(256), 0, stream>>>(x, xt);
  fused_dcn_kernel<<<dim3(NBATCH * 64), dim3(256), 0, stream>>>(xt, wsA, wsB, b_off, b_def, out);
}

// Round 4
// 132.622 us; speedup vs baseline: 1.0797x; 1.0797x over previous
//
#include <hip/hip_runtime.h>
#include <math.h>

typedef _Float16 f16;
typedef __attribute__((ext_vector_type(2))) _Float16 f16x2;
typedef __attribute__((ext_vector_type(4))) _Float16 f16x4;
typedef __attribute__((ext_vector_type(8))) _Float16 f16x8;
typedef __attribute__((ext_vector_type(4))) float f32x4;

#define NBATCH 8
#define WSA_ELE 36864      // 32*1152 (w_off padded to 32 rows, k-major, frag-swizzled)
#define WSB_ELE 147456     // 128*1152 (w_def, k-major, frag-swizzled)
// workspace byte offsets
#define OFF_WSB  73728
#define OFF_XT   368640

__device__ __forceinline__ void gload_lds16(const f16* gsrc, f16* ldst) {
  // wave-uniform LDS base; HW adds lane*16
  __builtin_amdgcn_global_load_lds(
      (const __attribute__((address_space(1))) unsigned int*)gsrc,
      (__attribute__((address_space(3))) unsigned int*)ldst, 16, 0, 0);
}

// ---------------- prep: weights -> fp16, k-major, MFMA-fragment-swizzled ----------------
// swizzled element e = ((ch*NFRAG + mt)*64 + lane)*8 + j holds
// W[row = mt*16 + (lane&15)][kidx = ch*32 + (lane>>4)*8 + j], kidx = k*128 + cc.
__global__ __launch_bounds__(256) void prep_w_kernel(const float* __restrict__ w_off,
                                                     const float* __restrict__ w_def,
                                                     f16* __restrict__ wsA,
                                                     f16* __restrict__ wsB) {
  int i = blockIdx.x * 256 + threadIdx.x;
  if (i < WSA_ELE) {
    int j = i & 7, lane = (i >> 3) & 63, fm = i >> 9;
    int ch = fm >> 1, mt = fm & 1;
    int row = mt * 16 + (lane & 15);
    int kidx = ch * 32 + (lane >> 4) * 8 + j;
    int k = kidx >> 7, cc = kidx & 127;
    float v = (row < 27) ? w_off[row * 1152 + cc * 9 + k] : 0.0f;
    wsA[i] = (f16)v;
  } else {
    int e = i - WSA_ELE;
    int j = e & 7, lane = (e >> 3) & 63, fm = e >> 9;
    int ch = fm >> 3, mt = fm & 7;
    int row = mt * 16 + (lane & 15);
    int kidx = ch * 32 + (lane >> 4) * 8 + j;
    int k = kidx >> 7, cc = kidx & 127;
    wsB[e] = (f16)w_def[row * 1152 + cc * 9 + k];
  }
}

// ---------------- transpose: x NCHW fp32 -> x_t NHWC fp16 (vectorized) ----------------
__global__ __launch_bounds__(256) void transpose_kernel(const float* __restrict__ x,
                                                        f16* __restrict__ xt) {
  __shared__ __align__(16) f16 s_t[128 * 68];   // pitch 68: 8B-aligned rows
  const int t = threadIdx.x;
  const int b = blockIdx.x >> 6;
  const int pos0 = (blockIdx.x & 63) << 6;
  const float* xb = x + ((size_t)b << 19);
  #pragma unroll
  for (int it = 0; it < 8; ++it) {
    int i = it * 256 + t;
    int c = i >> 4, p4 = (i & 15) << 2;
    float4 v = *(const float4*)&xb[c * 4096 + pos0 + p4];
    f16x4 h = {(f16)v.x, (f16)v.y, (f16)v.z, (f16)v.w};
    *(f16x4*)&s_t[c * 68 + p4] = h;
  }
  __syncthreads();
  f16* xtb = xt + ((size_t)b << 19);
  #pragma unroll
  for (int it = 0; it < 8; ++it) {
    int i = it * 256 + t;
    int p = i >> 5, c4 = (i & 31) << 2;
    f16x4 h = {s_t[(c4    ) * 68 + p],
               s_t[(c4 + 1) * 68 + p],
               s_t[(c4 + 2) * 68 + p],
               s_t[(c4 + 3) * 68 + p]};
    *(f16x4*)&xtb[(size_t)(pos0 + p) * 128 + c4] = h;
  }
}

// ---------------- fused: offset conv (-> LDS) + bilinear table + DCN main loop ----------------
// One block per (b, ho). Phase 3 = round-2's proven LDS-staged A + reg-prefetched
// gathers, but with the T3/T4 counted-vmcnt schedule: raw s_barrier + vmcnt(2)
// (NOT __syncthreads' vmcnt(0) drain), A triple-buffered with distance-2 staging.
// Per body: [G(ch+1) issue | pack(ch) | MFMA(ch) | fence | stage A(ch+2) |
// vmcnt(2) | s_barrier]. vmcnt(2) leaves only the 2 just-issued stage loads in
// flight; everything older (stage(ch+1), G(ch+1)) is drained exactly when needed.
__global__ __launch_bounds__(256) void fused_dcn_kernel(const f16* __restrict__ xt,
                                                        const f16* __restrict__ wsA,
                                                        const f16* __restrict__ wsB,
                                                        const float* __restrict__ b_off,
                                                        const float* __restrict__ b_def,
                                                        float* __restrict__ out) {
  __shared__ float  s_off[27 * 65];             // offset-conv row, pitch 65 (conflict-free)
  __shared__ uint4  s_ofs[576];                 // per-(k,px) corner byte-offsets
  __shared__ float4 s_wt[576];                  // per-(k,px) modulated weights
  __shared__ __align__(16) f16 s_a[3][4096];    // 3 x 8 KB A triple-buffer
  const int t = threadIdx.x;
  const int b = blockIdx.x >> 6, ho = blockIdx.x & 63;
  const int lane = t & 63, wid = t >> 6;
  const int q = lane >> 4, li = lane & 15;
  const int px = (wid << 4) + li;
  const char* xtb = (const char*)xt + ((size_t)b << 20);

  // ---- phase 1: offset conv, M=32 (27 live rows), barrier-free im2col MFMA ----
  {
    f32x4 acc0 = {0.f, 0.f, 0.f, 0.f}, acc1 = {0.f, 0.f, 0.f, 0.f};
    for (int k = 0; k < 9; ++k) {
      const int ky = k / 3, kx = k - ky * 3;
      const int y = ho + ky - 1;
      const int xx = px + kx - 1;
      const bool valid = ((unsigned)y < 64u) && ((unsigned)xx < 64u);
      const int pos = min(max(y, 0), 63) * 64 + min(max(xx, 0), 63);
      const int voff = pos * 256 + q * 16;   // bytes; +c4*64 as imm below
      #pragma unroll
      for (int c4 = 0; c4 < 4; ++c4) {
        union { uint4 u; f16x8 v; } bu;
        bu.u = *(const uint4*)(xtb + voff + c4 * 64);
        if (!valid) { bu.u.x = 0u; bu.u.y = 0u; bu.u.z = 0u; bu.u.w = 0u; }
        const int ch = k * 4 + c4;
        f16x8 a0 = *(const f16x8*)&wsA[(ch * 2    ) * 512 + lane * 8];
        f16x8 a1 = *(const f16x8*)&wsA[(ch * 2 + 1) * 512 + lane * 8];
        acc0 = __builtin_amdgcn_mfma_f32_16x16x32_f16(a0, bu.v, acc0, 0, 0, 0);
        acc1 = __builtin_amdgcn_mfma_f32_16x16x32_f16(a1, bu.v, acc1, 0, 0, 0);
      }
    }
    #pragma unroll
    for (int mt = 0; mt < 2; ++mt) {
      f32x4 a = mt ? acc1 : acc0;
      #pragma unroll
      for (int r = 0; r < 4; ++r) {
        int oc = mt * 16 + q * 4 + r;
        if (oc < 27) {
          float v = a[r] + b_off[oc];
          if (oc >= 18) v = 1.0f / (1.0f + __expf(-v));
          s_off[oc * 65 + px] = v;
        }
      }
    }
  }
  __syncthreads();   // offset row ready in LDS

  // stage A(0) and A(1) now; the phase-2 __syncthreads below drains them (one-time)
  {
    const int seg = wid * 2;
    gload_lds16(wsB + seg * 512 + lane * 8,              &s_a[0][seg * 512]);
    gload_lds16(wsB + (seg + 1) * 512 + lane * 8,        &s_a[0][(seg + 1) * 512]);
    gload_lds16(wsB + 4096 + seg * 512 + lane * 8,       &s_a[1][seg * 512]);
    gload_lds16(wsB + 4096 + (seg + 1) * 512 + lane * 8, &s_a[1][(seg + 1) * 512]);
  }

  // ---- phase 2: bilinear table (ci-invariant corner offsets + premultiplied weights) ----
  for (int f = t; f < 576; f += 256) {
    int k = f >> 6, p = f & 63;
    int ky = k / 3, kx = k - ky * 3;
    float oy = s_off[(2 * k    ) * 65 + p];
    float ox = s_off[(2 * k + 1) * 65 + p];
    float m  = s_off[(18 + k   ) * 65 + p];
    float py  = oy + (float)(ho + ky - 1);
    float pxf = ox + (float)(p + kx - 1);
    float y0f = floorf(py), x0f = floorf(pxf);
    float wy = py - y0f, wx = pxf - x0f;
    int y0 = (int)y0f, x0 = (int)x0f;
    int y1 = y0 + 1, x1 = x0 + 1;
    bool y0v = (unsigned)y0 < 64u, y1v = (unsigned)y1 < 64u;
    bool x0v = (unsigned)x0 < 64u, x1v = (unsigned)x1 < 64u;
    int y0c = min(max(y0, 0), 63), y1c = min(max(y1, 0), 63);
    int x0c = min(max(x0, 0), 63), x1c = min(max(x1, 0), 63);
    uint4 o4;
    o4.x = (unsigned)((y0c * 64 + x0c) * 256);
    o4.y = (unsigned)((y0c * 64 + x1c) * 256);
    o4.z = (unsigned)((y1c * 64 + x0c) * 256);
    o4.w = (unsigned)((y1c * 64 + x1c) * 256);
    float4 w4;
    w4.x = (y0v && x0v) ? (1.f - wy) * (1.f - wx) * m : 0.f;
    w4.y = (y0v && x1v) ? (1.f - wy) * wx         * m : 0.f;
    w4.z = (y1v && x0v) ? wy         * (1.f - wx) * m : 0.f;
    w4.w = (y1v && x1v) ? wy         * wx         * m : 0.f;
    s_ofs[f] = o4;
    s_wt[f]  = w4;
  }
  __syncthreads();   // table ready + A(0)/A(1) staging drained

  // ---- phase 3: counted-vmcnt pipelined main loop ----
  f32x4 acc[8];
  #pragma unroll
  for (int mt = 0; mt < 8; ++mt) acc[mt] = (f32x4){0.f, 0.f, 0.f, 0.f};

  typedef union { uint4 u; f16x8 v; f16x2 h[4]; } AU;
  AU Gc[4], Gn[4];

  // prologue gathers for chunk 0 (k=0, c4=0)
  {
    const uint4 o4 = s_ofs[px];
    const unsigned add = q * 16;
    Gc[0].u = *(const uint4*)(xtb + o4.x + add);
    Gc[1].u = *(const uint4*)(xtb + o4.y + add);
    Gc[2].u = *(const uint4*)(xtb + o4.z + add);
    Gc[3].u = *(const uint4*)(xtb + o4.w + add);
  }

  #pragma unroll 3
  for (int ch = 0; ch < 36; ++ch) {
    // 1) issue next chunk's gathers (consumed next body; fences pin them here)
    if (ch < 35) {
      const int kn = (ch + 1) >> 2, c4n = (ch + 1) & 3;
      const uint4 o4 = s_ofs[kn * 64 + px];
      const unsigned add = q * 16 + c4n * 64;
      Gn[0].u = *(const uint4*)(xtb + o4.x + add);
      Gn[1].u = *(const uint4*)(xtb + o4.y + add);
      Gn[2].u = *(const uint4*)(xtb + o4.z + add);
      Gn[3].u = *(const uint4*)(xtb + o4.w + add);
    }
    // 2) pack current chunk's B fragment (compiler auto-waits G(ch), counted)
    const int k = ch >> 2;
    const float4 w4 = s_wt[k * 64 + px];
    const f16 h0 = (f16)w4.x, h1 = (f16)w4.y, h2 = (f16)w4.z, h3 = (f16)w4.w;
    const f16x2 wp0 = {h0, h0}, wp1 = {h1, h1}, wp2 = {h2, h2}, wp3 = {h3, h3};
    union { f16x2 h[4]; f16x8 v; } bf;
    #pragma unroll
    for (int i = 0; i < 4; ++i) {
      f16x2 s = Gc[0].h[i] * wp0;
      s = s + Gc[1].h[i] * wp1;
      s = s + Gc[2].h[i] * wp2;
      s = s + Gc[3].h[i] * wp3;
      bf.h[i] = s;
    }
    // 3) MFMA from current LDS buffer (A(ch) guaranteed by previous barrier)
    const f16* ab = &s_a[ch % 3][0];
    #pragma unroll
    for (int mt = 0; mt < 8; ++mt) {
      f16x8 a = *(const f16x8*)&ab[(mt * 64 + lane) * 8];
      acc[mt] = __builtin_amdgcn_mfma_f32_16x16x32_f16(a, bf.v, acc[mt], 0, 0, 0);
    }
    // 4) stage A(ch+2) LAST (pinned), then counted-vmcnt + raw barrier
    if (ch < 34) {
      asm volatile("" ::: "memory");   // pin stage issue after the gathers
      const int nb = (ch + 2) % 3;
      const int seg = wid * 2;
      const f16* src = wsB + (ch + 2) * 4096;
      gload_lds16(src + seg * 512 + lane * 8,       &s_a[nb][seg * 512]);
      gload_lds16(src + (seg + 1) * 512 + lane * 8, &s_a[nb][(seg + 1) * 512]);
    }
    if (ch < 35) {
      // leave only the 2 just-issued stage loads in flight; drains stage(ch+1)+G(ch+1)
      asm volatile("s_waitcnt vmcnt(2)" ::: "memory");
      __builtin_amdgcn_s_barrier();
      asm volatile("" ::: "memory");   // no hoisting of next body's LDS reads
    }
    #pragma unroll
    for (int i = 0; i < 4; ++i) Gc[i] = Gn[i];
  }

  float* o = out + (size_t)b * 128 * 4096 + ho * 64 + px;
  #pragma unroll
  for (int mt = 0; mt < 8; ++mt) {
    #pragma unroll
    for (int r = 0; r < 4; ++r) {
      int oc = mt * 16 + q * 4 + r;
      o[oc * 4096] = acc[mt][r] + b_def[oc];
    }
  }
}

extern "C" void kernel_launch(void* const* d_in, const int* in_sizes, int n_in,
                              void* d_out, int out_size, void* d_ws, size_t ws_size,
                              hipStream_t stream) {
  const float* x     = (const float*)d_in[0];
  const float* w_off = (const float*)d_in[1];
  const float* b_off = (const float*)d_in[2];
  const float* w_def = (const float*)d_in[3];
  const float* b_def = (const float*)d_in[4];
  float* out = (float*)d_out;

  f16* wsA = (f16*)d_ws;
  f16* wsB = (f16*)((char*)d_ws + OFF_WSB);
  f16* xt  = (f16*)((char*)d_ws + OFF_XT);

  prep_w_kernel<<<dim3((WSA_ELE + WSB_ELE) / 256), dim3(256), 0, stream>>>(w_off, w_def, wsA, wsB);
  transpose_kernel<<<dim3(NBATCH * 64), dim3(256), 0, stream>>>(x, xt);
  fused_dcn_kernel<<<dim3(NBATCH * 64), dim3(256), 0, stream>>>(xt, wsA, wsB, b_off, b_def, out);
}

// Round 5
// 127.978 us; speedup vs baseline: 1.1189x; 1.0363x over previous
//
#include <hip/hip_runtime.h>
#include <math.h>

typedef _Float16 f16;
typedef __attribute__((ext_vector_type(2))) _Float16 f16x2;
typedef __attribute__((ext_vector_type(4))) _Float16 f16x4;
typedef __attribute__((ext_vector_type(8))) _Float16 f16x8;
typedef __attribute__((ext_vector_type(4))) float f32x4;

#define NBATCH 8
#define WSA_ELE 36864      // 32*1152 (w_off padded to 32 rows, k-major, frag-swizzled)
#define WSB_ELE 147456     // 128*1152 (w_def, k-major, frag-swizzled)
#define PREP_BLOCKS 720    // (WSA_ELE + WSB_ELE) / 256
// workspace byte offsets
#define OFF_WSB  73728
#define OFF_XT   368640

__device__ __forceinline__ void gload_lds16(const f16* gsrc, f16* ldst) {
  // wave-uniform LDS base; HW adds lane*16
  __builtin_amdgcn_global_load_lds(
      (const __attribute__((address_space(1))) unsigned int*)gsrc,
      (__attribute__((address_space(3))) unsigned int*)ldst, 16, 0, 0);
}

// ---------------- merged prep (weights -> fp16 frag-swizzled) + transpose ----------------
// blocks [0, PREP_BLOCKS): weight prep.  blocks [PREP_BLOCKS, +512): x NCHW fp32 -> NHWC fp16.
__global__ __launch_bounds__(256) void prep_transpose_kernel(const float* __restrict__ w_off,
                                                             const float* __restrict__ w_def,
                                                             f16* __restrict__ wsA,
                                                             f16* __restrict__ wsB,
                                                             const float* __restrict__ x,
                                                             f16* __restrict__ xt) {
  __shared__ __align__(16) f16 s_t[128 * 68];   // pitch 68: 8B-aligned rows
  const int t = threadIdx.x;
  if (blockIdx.x < PREP_BLOCKS) {
    int i = blockIdx.x * 256 + t;
    if (i < WSA_ELE) {
      int j = i & 7, lane = (i >> 3) & 63, fm = i >> 9;
      int ch = fm >> 1, mt = fm & 1;
      int row = mt * 16 + (lane & 15);
      int kidx = ch * 32 + (lane >> 4) * 8 + j;
      int k = kidx >> 7, cc = kidx & 127;
      float v = (row < 27) ? w_off[row * 1152 + cc * 9 + k] : 0.0f;
      wsA[i] = (f16)v;
    } else {
      int e = i - WSA_ELE;
      int j = e & 7, lane = (e >> 3) & 63, fm = e >> 9;
      int ch = fm >> 3, mt = fm & 7;
      int row = mt * 16 + (lane & 15);
      int kidx = ch * 32 + (lane >> 4) * 8 + j;
      int k = kidx >> 7, cc = kidx & 127;
      wsB[e] = (f16)w_def[row * 1152 + cc * 9 + k];
    }
    return;
  }
  const int bid = blockIdx.x - PREP_BLOCKS;
  const int b = bid >> 6;
  const int pos0 = (bid & 63) << 6;
  const float* xb = x + ((size_t)b << 19);
  #pragma unroll
  for (int it = 0; it < 8; ++it) {
    int i = it * 256 + t;
    int c = i >> 4, p4 = (i & 15) << 2;
    float4 v = *(const float4*)&xb[c * 4096 + pos0 + p4];
    f16x4 h = {(f16)v.x, (f16)v.y, (f16)v.z, (f16)v.w};
    *(f16x4*)&s_t[c * 68 + p4] = h;
  }
  __syncthreads();
  f16* xtb = xt + ((size_t)b << 19);
  #pragma unroll
  for (int it = 0; it < 8; ++it) {
    int i = it * 256 + t;
    int p = i >> 5, c4 = (i & 31) << 2;
    f16x4 h = {s_t[(c4    ) * 68 + p],
               s_t[(c4 + 1) * 68 + p],
               s_t[(c4 + 2) * 68 + p],
               s_t[(c4 + 3) * 68 + p]};
    *(f16x4*)&xtb[(size_t)(pos0 + p) * 128 + c4] = h;
  }
}

// ---------------- fused: offset conv (-> LDS) + bilinear table + DCN main loop ----------------
// One block per (b, ho), decoded XCD-aware: b = blockIdx&7, ho = blockIdx>>3, so
// all 64 blocks of batch b land on XCD b (round-robin dispatch) and the XCD's L2
// holds exactly one 1MB image + the 288KB weights -> gathers L2-hit instead of
// paying ~900cy HBM misses. Phase 3 = proven LDS-dbuf A staging + 1-chunk-ahead
// register-prefetched gathers (R2 structure, 56.6us).
__global__ __launch_bounds__(256) void fused_dcn_kernel(const f16* __restrict__ xt,
                                                        const f16* __restrict__ wsA,
                                                        const f16* __restrict__ wsB,
                                                        const float* __restrict__ b_off,
                                                        const float* __restrict__ b_def,
                                                        float* __restrict__ out) {
  __shared__ float  s_off[27 * 65];             // offset-conv row, pitch 65 (conflict-free)
  __shared__ uint4  s_ofs[576];                 // per-(k,px) corner byte-offsets
  __shared__ float4 s_wt[576];                  // per-(k,px) modulated weights
  __shared__ __align__(16) f16 s_a[2][4096];    // 2 x 8 KB A double-buffer
  const int t = threadIdx.x;
  const int b = blockIdx.x & 7, ho = blockIdx.x >> 3;   // XCD = batch
  const int lane = t & 63, wid = t >> 6;
  const int q = lane >> 4, li = lane & 15;
  const int px = (wid << 4) + li;
  const char* xtb = (const char*)xt + ((size_t)b << 20);

  // stage chunk 0 of A early; drains at the phase-1 barrier
  {
    const int seg = wid * 2;
    gload_lds16(wsB + seg * 512 + lane * 8,       &s_a[0][seg * 512]);
    gload_lds16(wsB + (seg + 1) * 512 + lane * 8, &s_a[0][(seg + 1) * 512]);
  }

  // ---- phase 1: offset conv, M=32 (27 live rows), fully unrolled im2col MFMA ----
  // (occupancy is grid-capped at 2 blocks/CU -> VGPRs are free; full unroll lets
  //  the compiler hoist the 36 gather loads for ILP)
  {
    f32x4 acc0 = {0.f, 0.f, 0.f, 0.f}, acc1 = {0.f, 0.f, 0.f, 0.f};
    #pragma unroll
    for (int k = 0; k < 9; ++k) {
      const int ky = k / 3, kx = k - ky * 3;
      const int y = ho + ky - 1;
      const int xx = px + kx - 1;
      const bool valid = ((unsigned)y < 64u) && ((unsigned)xx < 64u);
      const int pos = min(max(y, 0), 63) * 64 + min(max(xx, 0), 63);
      const int voff = pos * 256 + q * 16;   // bytes; +c4*64 as imm below
      #pragma unroll
      for (int c4 = 0; c4 < 4; ++c4) {
        union { uint4 u; f16x8 v; } bu;
        bu.u = *(const uint4*)(xtb + voff + c4 * 64);
        if (!valid) { bu.u.x = 0u; bu.u.y = 0u; bu.u.z = 0u; bu.u.w = 0u; }
        const int ch = k * 4 + c4;
        f16x8 a0 = *(const f16x8*)&wsA[(ch * 2    ) * 512 + lane * 8];
        f16x8 a1 = *(const f16x8*)&wsA[(ch * 2 + 1) * 512 + lane * 8];
        acc0 = __builtin_amdgcn_mfma_f32_16x16x32_f16(a0, bu.v, acc0, 0, 0, 0);
        acc1 = __builtin_amdgcn_mfma_f32_16x16x32_f16(a1, bu.v, acc1, 0, 0, 0);
      }
    }
    #pragma unroll
    for (int mt = 0; mt < 2; ++mt) {
      f32x4 a = mt ? acc1 : acc0;
      #pragma unroll
      for (int r = 0; r < 4; ++r) {
        int oc = mt * 16 + q * 4 + r;
        if (oc < 27) {
          float v = a[r] + b_off[oc];
          if (oc >= 18) v = 1.0f / (1.0f + __expf(-v));
          s_off[oc * 65 + px] = v;
        }
      }
    }
  }
  __syncthreads();   // offset row ready + chunk-0 A staging drained

  // ---- phase 2: bilinear table (ci-invariant corner offsets + premultiplied weights) ----
  for (int f = t; f < 576; f += 256) {
    int k = f >> 6, p = f & 63;
    int ky = k / 3, kx = k - ky * 3;
    float oy = s_off[(2 * k    ) * 65 + p];
    float ox = s_off[(2 * k + 1) * 65 + p];
    float m  = s_off[(18 + k   ) * 65 + p];
    float py  = oy + (float)(ho + ky - 1);
    float pxf = ox + (float)(p + kx - 1);
    float y0f = floorf(py), x0f = floorf(pxf);
    float wy = py - y0f, wx = pxf - x0f;
    int y0 = (int)y0f, x0 = (int)x0f;
    int y1 = y0 + 1, x1 = x0 + 1;
    bool y0v = (unsigned)y0 < 64u, y1v = (unsigned)y1 < 64u;
    bool x0v = (unsigned)x0 < 64u, x1v = (unsigned)x1 < 64u;
    int y0c = min(max(y0, 0), 63), y1c = min(max(y1, 0), 63);
    int x0c = min(max(x0, 0), 63), x1c = min(max(x1, 0), 63);
    uint4 o4;
    o4.x = (unsigned)((y0c * 64 + x0c) * 256);
    o4.y = (unsigned)((y0c * 64 + x1c) * 256);
    o4.z = (unsigned)((y1c * 64 + x0c) * 256);
    o4.w = (unsigned)((y1c * 64 + x1c) * 256);
    float4 w4;
    w4.x = (y0v && x0v) ? (1.f - wy) * (1.f - wx) * m : 0.f;
    w4.y = (y0v && x1v) ? (1.f - wy) * wx         * m : 0.f;
    w4.z = (y1v && x0v) ? wy         * (1.f - wx) * m : 0.f;
    w4.w = (y1v && x1v) ? wy         * wx         * m : 0.f;
    s_ofs[f] = o4;
    s_wt[f]  = w4;
  }
  __syncthreads();   // table ready

  // ---- phase 3: LDS-dbuf A + one-chunk-ahead register-prefetched gathers ----
  f32x4 acc[8];
  #pragma unroll
  for (int mt = 0; mt < 8; ++mt) acc[mt] = (f32x4){0.f, 0.f, 0.f, 0.f};

  union U4 { uint4 u; f16x2 h[4]; };
  U4 d0c, d1c, d2c, d3c;

  // prefetch chunk 0 gathers (k=0, c4=0)
  {
    const uint4 o4 = s_ofs[px];
    d0c.u = *(const uint4*)(xtb + o4.x + q * 16);
    d1c.u = *(const uint4*)(xtb + o4.y + q * 16);
    d2c.u = *(const uint4*)(xtb + o4.z + q * 16);
    d3c.u = *(const uint4*)(xtb + o4.w + q * 16);
  }

  #pragma unroll 1
  for (int ch = 0; ch < 36; ++ch) {
    const int k = ch >> 2;
    // stage A for next chunk into the other LDS buffer
    if (ch < 35) {
      const int nb = (ch + 1) & 1;
      const int seg = wid * 2;
      const f16* src = wsB + (ch + 1) * 4096;
      gload_lds16(src + seg * 512 + lane * 8,       &s_a[nb][seg * 512]);
      gload_lds16(src + (seg + 1) * 512 + lane * 8, &s_a[nb][(seg + 1) * 512]);
    }
    // issue next chunk's gathers NOW (used a full iteration later)
    U4 d0n, d1n, d2n, d3n;
    if (ch < 35) {
      const int kn = (ch + 1) >> 2, c4n = (ch + 1) & 3;
      const uint4 o4n = s_ofs[kn * 64 + px];
      const unsigned add = q * 16 + c4n * 64;
      d0n.u = *(const uint4*)(xtb + o4n.x + add);
      d1n.u = *(const uint4*)(xtb + o4n.y + add);
      d2n.u = *(const uint4*)(xtb + o4n.z + add);
      d3n.u = *(const uint4*)(xtb + o4n.w + add);
    }
    // pack current chunk's B fragment
    const float4 w4 = s_wt[k * 64 + px];
    const f16 h0 = (f16)w4.x, h1 = (f16)w4.y, h2 = (f16)w4.z, h3 = (f16)w4.w;
    const f16x2 wp0 = {h0, h0}, wp1 = {h1, h1}, wp2 = {h2, h2}, wp3 = {h3, h3};
    union { f16x2 h[4]; f16x8 v; } bf;
    #pragma unroll
    for (int i = 0; i < 4; ++i) {
      f16x2 s = d0c.h[i] * wp0;
      s = s + d1c.h[i] * wp1;
      s = s + d2c.h[i] * wp2;
      s = s + d3c.h[i] * wp3;
      bf.h[i] = s;
    }
    const f16* ab = &s_a[ch & 1][0];
    #pragma unroll
    for (int mt = 0; mt < 8; ++mt) {
      f16x8 a = *(const f16x8*)&ab[(mt * 64 + lane) * 8];
      acc[mt] = __builtin_amdgcn_mfma_f32_16x16x32_f16(a, bf.v, acc[mt], 0, 0, 0);
    }
    __syncthreads();   // drain staging (+in-flight gathers land under MFMA work)
    if (ch < 35) { d0c = d0n; d1c = d1n; d2c = d2n; d3c = d3n; }
  }

  float* o = out + (size_t)b * 128 * 4096 + ho * 64 + px;
  #pragma unroll
  for (int mt = 0; mt < 8; ++mt) {
    #pragma unroll
    for (int r = 0; r < 4; ++r) {
      int oc = mt * 16 + q * 4 + r;
      o[oc * 4096] = acc[mt][r] + b_def[oc];
    }
  }
}

extern "C" void kernel_launch(void* const* d_in, const int* in_sizes, int n_in,
                              void* d_out, int out_size, void* d_ws, size_t ws_size,
                              hipStream_t stream) {
  const float* x     = (const float*)d_in[0];
  const float* w_off = (const float*)d_in[1];
  const float* b_off = (const float*)d_in[2];
  const float* w_def = (const float*)d_in[3];
  const float* b_def = (const float*)d_in[4];
  float* out = (float*)d_out;

  f16* wsA = (f16*)d_ws;
  f16* wsB = (f16*)((char*)d_ws + OFF_WSB);
  f16* xt  = (f16*)((char*)d_ws + OFF_XT);

  prep_transpose_kernel<<<dim3(PREP_BLOCKS + NBATCH * 64), dim3(256), 0, stream>>>(
      w_off, w_def, wsA, wsB, x, xt);
  fused_dcn_kernel<<<dim3(NBATCH * 64), dim3(256), 0, stream>>>(xt, wsA, wsB, b_off, b_def, out);
}